// Round 3
// baseline (32910.098 us; speedup 1.0000x reference)
//
#include <hip/hip_runtime.h>
#include <stdint.h>

// ---------------------------------------------------------------------------
// Bidirectional 3-layer LSTM, B=32 T=2048 U=256 H4=1024.
// Round-3 = round-2 architecture, hardened (never measured due to infra):
//  - rec_wave: 64 autonomous waves (32 per direction). Wave w owns one
//    32x32x16 MFMA tile = 8 units x 4 gates. Recurrent weights VGPR-resident.
//    h exchanged via a tagged 8-deep ring of 64-bit words
//    [2 x bf16 | u32 step-tag], atomic relaxed agent loads/stores.
//    Consumer loads land directly as MFMA A-fragments (no LDS staging,
//    no barriers, no flags). Gate mixing via per-wave LDS transpose.
//  - deltas vs round-2: (a) VGPR-lean tagged validate (keep lo dwords only,
//    fold tags into a running mismatch accumulator; peak live ~170 vs ~240);
//    (b) ring publish stores issue before xseq/dout output stores.
//  - deadlock safety: ring depth 8 + per-role progress counters checked
//    every 4 steps with margin 3; canary word per producer prefilters spins.
// ---------------------------------------------------------------------------

typedef unsigned short u16;
typedef unsigned int   u32;
typedef unsigned long long u64;
typedef __attribute__((ext_vector_type(8)))  short short8;   // 8 x bf16
typedef __attribute__((ext_vector_type(4)))  u32  u32x4;
typedef __attribute__((ext_vector_type(16))) float f32x16;

#define B_    32
#define T_    2048
#define CHUNK 256
#define RING  8

__device__ __forceinline__ float bf2f(u16 v){ u32 u = ((u32)v) << 16; return __builtin_bit_cast(float, u); }
__device__ __forceinline__ u16 f2bf(float f){
  u32 u = __builtin_bit_cast(u32, f);
  return (u16)((u + 0x7FFFu + ((u >> 16) & 1u)) >> 16);   // RNE
}
__device__ __forceinline__ float sigm(float x){
  return __builtin_amdgcn_rcpf(1.f + __builtin_amdgcn_exp2f(-1.4426950408889634f * x));
}
__device__ __forceinline__ float tanh_(float x){
  x = fminf(fmaxf(x, -30.f), 30.f);
  float t = __builtin_amdgcn_exp2f(2.8853900817779268f * x);
  return (t - 1.f) * __builtin_amdgcn_rcpf(t + 1.f);
}

// global -> LDS async, 16B/lane (xz_gemm staging)
__device__ __forceinline__ void gl2lds16(const void* g, void* s){
  __builtin_amdgcn_global_load_lds(
      (const __attribute__((address_space(1))) u32*)(uintptr_t)g,
      (__attribute__((address_space(3))) u32*)(u32)(uintptr_t)s, 16, 0, 0);
}

// ------------------------- prep: U fragment pack ---------------------------
// e = layer<<19 | dir<<18 | w<<13 | kt<<9 | l<<3 | j  (w: 0..31 wave/tile)
// B-frag: col = l&31 (virtual col c = gate*8+uu), k = kt*16 + (l>>5)*8 + j
__global__ void prep_upack(const float* __restrict__ U0f, const float* __restrict__ U0b,
                           const float* __restrict__ Uf,  const float* __restrict__ Ub,
                           u16* __restrict__ upack)
{
  int e = blockIdx.x * 256 + threadIdx.x;      // < 1,572,864
  int j  = e & 7;
  int l  = (e >> 3) & 63;
  int kt = (e >> 9) & 15;
  int w  = (e >> 13) & 31;
  int dir   = (e >> 18) & 1;
  int layer = e >> 19;
  int cc   = l & 31;
  int colg = (cc >> 3) * 256 + w * 8 + (cc & 7);   // gate*256 + unit
  int k    = kt * 16 + ((l >> 5) & 1) * 8 + j;
  const float* src = (layer == 0) ? (dir ? U0b : U0f)
                                  : ((dir ? Ub : Uf) + (size_t)(layer - 1) * (256 * 1024));
  upack[e] = f2bf(src[(size_t)k * 1024 + colg]);
}

// ------------------------- prep: W transpose -------------------------------
__global__ void prep_wt(const float* __restrict__ Wf, const float* __restrict__ Wb,
                        u16* __restrict__ wt)
{
  int e = blockIdx.x * 256 + threadIdx.x;       // < 2,097,152
  int k    = e & 511;
  int colg = (e >> 9) & 1023;
  int ld   = e >> 19;                           // (layer-1)*2 + dir
  int layer = ld >> 1, dir = ld & 1;
  const float* src = (dir ? Wb : Wf) + (size_t)layer * (512 * 1024);
  wt[e] = f2bf(src[(size_t)k * 1024 + colg]);
}

// ------------------------- prep: x transpose (layer 0) ---------------------
// xT[t][pos] = x[batch(pos)][t],  batch(pos) = (p&3)+8*((p>>2)&3)+4*(p>>4)
__global__ void prep_xT(const float* __restrict__ x, float* __restrict__ xT)
{
  int e = blockIdx.x * 256 + threadIdx.x;       // < 65536
  int t = e >> 5, pos = e & 31;
  int b = (pos & 3) + 8 * ((pos >> 2) & 3) + 4 * (pos >> 4);
  xT[t * 32 + pos] = x[(size_t)b * T_ + t];
}

__global__ void ws_fail(float* o){ o[0] = -1.0e6f; }

// ------------------------- xz GEMM (layers 1,2) ----------------------------
__global__ __launch_bounds__(256) void xz_gemm(
    const u16* __restrict__ xs,      // [T][32 pos][512] bf16
    const u16* __restrict__ wt,      // [4][1024][512] bf16 (B^T panels)
    const float* __restrict__ bf_,   // [2][1024]
    const float* __restrict__ bb_,
    u16* __restrict__ xz,            // [2][CHUNK][1024 vcol][32 loadpos] bf16
    int layer, int s0)
{
  const int bm = blockIdx.x;         // 64 M-tiles
  const int bn = blockIdx.y;         // 8 N-tiles
  const int dir = blockIdx.z;
  const int tid = threadIdx.x, w = tid >> 6, l = tid & 63;
  const int wm = w >> 1, wn = w & 1;
  __shared__ u16 As[128 * 64];
  __shared__ u16 Bs[128 * 64];
  const u16* wpanel = wt + (size_t)((layer - 1) * 2 + dir) * (1024 * 512);
  const float* bias = (dir ? bb_ : bf_) + (size_t)(layer - 1) * 1024;
  f32x16 acc00{}, acc01{}, acc10{}, acc11{};

  for (int k0 = 0; k0 < 8; k0++){
    #pragma unroll
    for (int i = 0; i < 4; i++){               // A tile (128 rows x 64 k)
      int inst = i * 4 + w;
      int R = bm * 128 + inst * 8 + (l >> 3);
      int sl = R >> 5, b = R & 31;
      int t = dir ? (T_ - 1 - (s0 + sl)) : (s0 + sl);
      const u16* g = xs + ((size_t)(t * 32 + b) * 512 + k0 * 64 + (l & 7) * 8);
      gl2lds16(g, (void*)(As + inst * 512));
    }
    #pragma unroll
    for (int i = 0; i < 4; i++){               // B tile (128 cols x 64 k)
      int inst = i * 4 + w;
      int colg = bn * 128 + inst * 8 + (l >> 3);
      const u16* g = wpanel + ((size_t)colg * 512 + k0 * 64 + (l & 7) * 8);
      gl2lds16(g, (void*)(Bs + inst * 512));
    }
    asm volatile("s_waitcnt vmcnt(0)" ::: "memory");
    __syncthreads();
    #pragma unroll
    for (int kt = 0; kt < 4; kt++){
      int ko = kt * 16 + (l >> 5) * 8;
      short8 a0 = *(const short8*)(As + (wm * 64 +      (l & 31)) * 64 + ko);
      short8 a1 = *(const short8*)(As + (wm * 64 + 32 + (l & 31)) * 64 + ko);
      short8 b0 = *(const short8*)(Bs + (wn * 64 +      (l & 31)) * 64 + ko);
      short8 b1 = *(const short8*)(Bs + (wn * 64 + 32 + (l & 31)) * 64 + ko);
      acc00 = __builtin_amdgcn_mfma_f32_32x32x16_bf16(a0, b0, acc00, 0, 0, 0);
      acc01 = __builtin_amdgcn_mfma_f32_32x32x16_bf16(a0, b1, acc01, 0, 0, 0);
      acc10 = __builtin_amdgcn_mfma_f32_32x32x16_bf16(a1, b0, acc10, 0, 0, 0);
      acc11 = __builtin_amdgcn_mfma_f32_32x32x16_bf16(a1, b1, acc11, 0, 0, 0);
    }
    __syncthreads();
  }
  // epilogue -> xz[(dir,sl)][vcol][loadpos], loadpos = inverse batch permutation
  const int lrow = 4 * (l >> 5);
  auto epi = [&](const f32x16& A, int mi, int ni){
    int colg = bn * 128 + wn * 64 + ni * 32 + (l & 31);
    float bv = bias[colg];
    int unit = colg & 255, gate = colg >> 8;
    int vcol = (unit >> 3) * 32 + gate * 8 + (unit & 7);
    #pragma unroll
    for (int r = 0; r < 16; r++){
      int row = wm * 64 + mi * 32 + (r & 3) + 8 * (r >> 2) + lrow;
      int R = bm * 128 + row;
      int sl = R >> 5, b = R & 31;
      int pos = (b & 3) + ((b >> 3) & 3) * 4 + ((b >> 2) & 1) * 16;
      xz[((size_t)(dir * CHUNK + sl) * 1024 + vcol) * 32 + pos] = f2bf(A[r] + bv);
    }
  };
  epi(acc00, 0, 0); epi(acc01, 0, 1); epi(acc10, 1, 0); epi(acc11, 1, 1);
}

// ------------------------- recurrence --------------------------------------
// grid = 16 WGs x 256 thr. dir = bid>>3, wave w = (bid&7)*4 + wid (0..31).
// Wave: 32 virtual cols (c = gate*8+uu) over units w*8..w*8+8, all 32 batch.
// Ring word (pair p, batch b): lo = bf16(h[2p]) | bf16(h[2p+1])<<16, hi = tag.
__global__ __launch_bounds__(256, 1) void rec_wave(
    int layer, int s0, int nsteps,
    const float* __restrict__ xT,
    const float* __restrict__ w0f, const float* __restrict__ w0b,
    const float* __restrict__ b0f, const float* __restrict__ b0b,
    const u16* __restrict__ upack,
    const u16* __restrict__ xz,      // [2][CHUNK][1024][32]
    u16*  __restrict__ xseq_out,     // layers 0,1: [T][32][512]
    float* __restrict__ dout,        // layer 2
    u64*  __restrict__ ring,         // [2][RING][4096]
    float* __restrict__ state_c,     // [2][256][32]
    int*  __restrict__ rawp)         // [64]
{
  const int tid = threadIdx.x;
  const int wid = tid >> 6, l = tid & 63;
  const int dir = blockIdx.x >> 3;
  const int w   = (blockIdx.x & 7) * 4 + wid;     // 0..31
  const int role = dir * 32 + w;
  const int c = l & 31, half = l >> 5;
  const int g = c >> 3, uu = c & 7;
  const int unit = w * 8 + uu;
  const int b0 = g * 8 + half * 4;                // 4 consecutive batches

  __shared__ float zt[4][32 * 33];
  float* myz = zt[wid];

  // resident recurrent-weight B fragments (64 VGPR)
  short8 Bf[16];
  #pragma unroll
  for (int kt = 0; kt < 16; kt++)
    Bf[kt] = *(const short8*)(upack +
        ((size_t)((((layer * 2 + dir) * 32 + w) * 16 + kt) * 64 + l)) * 8);

  float cst[4];
  #pragma unroll
  for (int i = 0; i < 4; i++)
    cst[i] = state_c[(dir * 256 + unit) * 32 + b0 + i];

  float w0v = 0.f, b0v = 0.f;
  if (layer == 0){
    const float* W0 = dir ? w0b : w0f;
    const float* Bb = dir ? b0b : b0f;
    int colg = g * 256 + unit;
    w0v = W0[colg]; b0v = Bb[colg];
  }

  u64* myring = ring + (size_t)dir * RING * 4096;

  for (int ss = 0; ss < nsteps; ss++){
    const int s = s0 + ss;
    const int G = layer * T_ + s;                 // global step (tag)
    const int t = dir ? (T_ - 1 - s) : s;

    // ---- input-term -> even-chain accumulator init (independent of exchange)
    f32x16 acce{}, acco{};
    if (layer == 0){
      const float4* xp = (const float4*)(xT + t * 32 + half * 16);
      float4 x0 = xp[0], x1 = xp[1], x2 = xp[2], x3 = xp[3];
      float xv[16] = {x0.x,x0.y,x0.z,x0.w, x1.x,x1.y,x1.z,x1.w,
                      x2.x,x2.y,x2.z,x2.w, x3.x,x3.y,x3.z,x3.w};
      #pragma unroll
      for (int r = 0; r < 16; r++) acce[r] = xv[r] * w0v + b0v;
    } else {
      const u16* xp = xz + ((size_t)((dir * CHUNK + ss) * 1024 + w * 32 + c)) * 32 + half * 16;
      short8 xa = *(const short8*)xp;
      short8 xb = *(const short8*)(xp + 8);
      #pragma unroll
      for (int r = 0; r < 8; r++){ acce[r] = bf2f((u16)xa[r]); acce[r + 8] = bf2f((u16)xb[r]); }
    }

    u64* slotr = myring + (size_t)(G & 7) * 4096;

    // ---- canary: one word per producer wave (cheap spin; lane l<32 watches
    // producer wave l's word (pair 4l, batch l))
    if (l < 32){
      const u64* cw = slotr + l * 129;
      while ((u32)(__hip_atomic_load(cw, __ATOMIC_RELAXED, __HIP_MEMORY_SCOPE_AGENT) >> 32)
             != (u32)G) {}
    }

    // ---- full tagged pass: 64 u64 words -> 16 A-fragments (lo dwords only)
    u32x4 alo[16];
    bool ok;
    do {
      u32 bad = 0;
      #pragma unroll
      for (int kt = 0; kt < 16; kt++){
        u64 v0 = __hip_atomic_load(slotr + (kt * 8 + half * 4 + 0) * 32 + c,
                                   __ATOMIC_RELAXED, __HIP_MEMORY_SCOPE_AGENT);
        u64 v1 = __hip_atomic_load(slotr + (kt * 8 + half * 4 + 1) * 32 + c,
                                   __ATOMIC_RELAXED, __HIP_MEMORY_SCOPE_AGENT);
        u64 v2 = __hip_atomic_load(slotr + (kt * 8 + half * 4 + 2) * 32 + c,
                                   __ATOMIC_RELAXED, __HIP_MEMORY_SCOPE_AGENT);
        u64 v3 = __hip_atomic_load(slotr + (kt * 8 + half * 4 + 3) * 32 + c,
                                   __ATOMIC_RELAXED, __HIP_MEMORY_SCOPE_AGENT);
        alo[kt] = (u32x4){ (u32)v0, (u32)v1, (u32)v2, (u32)v3 };
        bad |= ((u32)(v0 >> 32) ^ (u32)G) | ((u32)(v1 >> 32) ^ (u32)G)
             | ((u32)(v2 >> 32) ^ (u32)G) | ((u32)(v3 >> 32) ^ (u32)G);
      }
      ok = (__ballot(bad != 0) == 0);
    } while (!ok);

    // consumption of h_G complete -> progress (early release for producers)
    if (l == 0)
      __hip_atomic_store(&rawp[role], G + 1, __ATOMIC_RELAXED, __HIP_MEMORY_SCOPE_AGENT);

    // ---- MFMA: z(tile) = h @ U(tile), two interleaved acc chains
    #pragma unroll
    for (int kt = 0; kt < 16; kt++){
      short8 A = __builtin_bit_cast(short8, alo[kt]);
      if (kt & 1) acco = __builtin_amdgcn_mfma_f32_32x32x16_bf16(A, Bf[kt], acco, 0, 0, 0);
      else        acce = __builtin_amdgcn_mfma_f32_32x32x16_bf16(A, Bf[kt], acce, 0, 0, 0);
    }

    // ---- per-wave LDS transpose: (16 rows x 1 col) -> (4 gates x 4 batches)
    #pragma unroll
    for (int r = 0; r < 16; r++){
      int row = (r & 3) + 8 * (r >> 2) + 4 * half;
      myz[row * 33 + c] = acce[r] + acco[r];
    }
    float zq[4][4];
    #pragma unroll
    for (int gg = 0; gg < 4; gg++)
      #pragma unroll
      for (int i = 0; i < 4; i++)
        zq[gg][i] = myz[(b0 + i) * 33 + gg * 8 + uu];

    // ---- gates (fp32 c in registers)
    float hv[4];
    #pragma unroll
    for (int i = 0; i < 4; i++){
      float si = sigm(zq[0][i]);
      float sf = sigm(zq[1][i]);
      float tg = tanh_(zq[2][i]);
      float so = sigm(zq[3][i]);
      cst[i] = sf * cst[i] + si * tg;
      hv[i]  = so * tanh_(cst[i]);
    }

    // ---- backpressure every 4 steps: writes G+1..G+4 destroy tags G-7..G-4
    if ((G & 3) == 0){
      int need = G - 3;
      bool bok;
      do {
        int v = 0x7fffffff;
        if (l < 32)
          v = __hip_atomic_load(&rawp[dir * 32 + l], __ATOMIC_RELAXED, __HIP_MEMORY_SCOPE_AGENT);
        bok = (__ballot(v < need) == 0);
      } while (!bok);
    }

    // ---- pair exchange; ring publish FIRST (critical path), outputs after
    float hpv[4];
    #pragma unroll
    for (int i = 0; i < 4; i++) hpv[i] = __shfl_xor(hv[i], 1);
    const int odd = uu & 1;
    const int p = w * 4 + (uu >> 1);
    u64* slotw = myring + (size_t)((G + 1) & 7) * 4096;
    float lo_f[2], hi_f[2];
    u32 hpk[2];
    #pragma unroll
    for (int k2 = 0; k2 < 2; k2++){
      int i = odd * 2 + k2;                       // even lane: batches b0,b0+1; odd: b0+2,b0+3
      lo_f[k2] = odd ? hpv[i] : hv[i];            // lo = even unit of the pair
      hi_f[k2] = odd ? hv[i] : hpv[i];
      hpk[k2]  = (u32)f2bf(lo_f[k2]) | ((u32)f2bf(hi_f[k2]) << 16);
    }
    #pragma unroll
    for (int k2 = 0; k2 < 2; k2++){
      int i = odd * 2 + k2;
      __hip_atomic_store(slotw + p * 32 + (b0 + i),
                         (u64)hpk[k2] | ((u64)(u32)(G + 1) << 32),
                         __ATOMIC_RELAXED, __HIP_MEMORY_SCOPE_AGENT);
    }
    #pragma unroll
    for (int k2 = 0; k2 < 2; k2++){
      int i = odd * 2 + k2;
      if (layer < 2){
        *(u32*)(xseq_out + (size_t)(t * 32 + b0 + i) * 512 + dir * 256 + w * 8 + (uu & ~1)) = hpk[k2];
      } else {
        *(float2*)(dout + ((size_t)(b0 + i) * T_ + t) * 512 + dir * 256 + w * 8 + (uu & ~1)) =
            make_float2(lo_f[k2], hi_f[k2]);
      }
    }

    // ---- final states (layer 2, last step)
    if (layer == 2 && s == T_ - 1){
      size_t sb = (size_t)B_ * T_ * 512;
      #pragma unroll
      for (int i = 0; i < 4; i++){
        dout[sb + (size_t)dir * 16384 +        (b0 + i) * 256 + unit] = hv[i];
        dout[sb + (size_t)dir * 16384 + 8192 + (b0 + i) * 256 + unit] = cst[i];
      }
    }
  }

  // persist c across launches
  #pragma unroll
  for (int i = 0; i < 4; i++)
    state_c[(dir * 256 + unit) * 32 + b0 + i] = cst[i];
}

// ------------------------- host --------------------------------------------
extern "C" void kernel_launch(void* const* d_in, const int* in_sizes, int n_in,
                              void* d_out, int out_size, void* d_ws, size_t ws_size,
                              hipStream_t stream)
{
  const float* x   = (const float*)d_in[0];
  const float* W0f = (const float*)d_in[1];
  const float* U0f = (const float*)d_in[2];
  const float* b0f = (const float*)d_in[3];
  const float* W0b = (const float*)d_in[4];
  const float* U0b = (const float*)d_in[5];
  const float* b0b = (const float*)d_in[6];
  const float* Wf  = (const float*)d_in[7];
  const float* Uf  = (const float*)d_in[8];
  const float* bf_ = (const float*)d_in[9];
  const float* Wb  = (const float*)d_in[10];
  const float* Ub  = (const float*)d_in[11];
  const float* bb_ = (const float*)d_in[12];
  float* out = (float*)d_out;

  char* base = (char*)d_ws;
  size_t off = 0;
  auto carve = [&](size_t bytes) -> char* {
    char* r = base + off;
    off += (bytes + 255) & ~(size_t)255;
    return r;
  };
  u16* xs0   = (u16*)carve((size_t)T_ * 32 * 512 * 2);        // 64MB
  u16* xs1   = (u16*)carve((size_t)T_ * 32 * 512 * 2);        // 64MB
  u16* xzbuf = (u16*)carve((size_t)2 * CHUNK * 1024 * 32 * 2);// 32MB
  u16* upack = (u16*)carve((size_t)1572864 * 2);              // 3MB
  u16* wt    = (u16*)carve((size_t)2097152 * 2);              // 4MB
  float* xT  = (float*)carve((size_t)T_ * 32 * 4);            // 256KB
  u64* ring  = (u64*)carve((size_t)2 * RING * 4096 * 8);      // 512KB
  float* stc = (float*)carve((size_t)2 * 256 * 32 * 4);       // 64KB
  int* rawp  = (int*)carve((size_t)64 * 4);
  char* zend = base + off;
  if (off > ws_size){
    ws_fail<<<1, 1, 0, stream>>>(out);
    return;
  }
  // zero ring (tag 0 == valid h_0 = 0), state_c, progress — every call
  hipMemsetAsync(ring, 0, (size_t)(zend - (char*)ring), stream);

  prep_upack<<<6144, 256, 0, stream>>>(U0f, U0b, Uf, Ub, upack);
  prep_wt<<<8192, 256, 0, stream>>>(Wf, Wb, wt);
  prep_xT<<<256, 256, 0, stream>>>(x, xT);

  // layer 0: single launch over all 2048 steps
  rec_wave<<<16, 256, 0, stream>>>(0, 0, T_, xT, W0f, W0b, b0f, b0b,
                                   upack, nullptr, xs0, nullptr, ring, stc, rawp);
  // layers 1,2: chunked GEMM + recurrence
  for (int layer = 1; layer <= 2; layer++){
    const u16* xsrc = (layer == 1) ? xs0 : xs1;
    u16* xdst = (layer == 1) ? xs1 : nullptr;
    for (int pch = 0; pch < T_ / CHUNK; pch++){
      xz_gemm<<<dim3(CHUNK * 32 / 128, 8, 2), 256, 0, stream>>>(
          xsrc, wt, bf_, bb_, xzbuf, layer, pch * CHUNK);
      rec_wave<<<16, 256, 0, stream>>>(layer, pch * CHUNK, CHUNK,
                                       nullptr, nullptr, nullptr, nullptr, nullptr,
                                       upack, xzbuf, xdst,
                                       (layer == 2) ? out : nullptr,
                                       ring, stc, rawp);
    }
  }
}